// Round 13
// baseline (234.219 us; speedup 1.0000x reference)
//
#include <hip/hip_runtime.h>

// MHA forward.  B=4 T=2048 DM=1024 H=16 DK=DV=64.  f32 in / f32 out.
// R23: attn same-g CU packing (index-only).
//   R22 post-mortem: attn wall = LONGEST block's serial tile chain.  With
//   complementary pairing (g, 7-g) the critical CU runs 28 of 32 tiles
//   SOLO (8 waves) after its 4-tile partner exits — matches Occ 27% and
//   ~5000 cyc/tile.  Now cu = pb & 255 (round-robin dispatch slot),
//   g = cu >> 5, bh = (cu&31)*2 + (pb>>8): both blocks on a CU share g,
//   so the g=7 wall CUs keep 16 waves for all 32 tiles.  XCD locality
//   kept (8 bh-sets/XCD).  Everything else = R22 (passed, 212.3 us):
//   cvtpk + R18-verified shfl PACK, counted-vmcnt dbuf, zero-init hoist,
//   max3 tree, packed exp; proj R17 XCD m-slice; cvt_x coalesced.

#define B_  4
#define T_  2048
#define DM_ 1024
#define H_  16
#define D_  64
#define DMO 1024   // out row stride = H_*D_

typedef unsigned short u16;
typedef unsigned int   u32;
typedef u16   u16x8  __attribute__((ext_vector_type(8)));
typedef short s16x8  __attribute__((ext_vector_type(8)));
typedef float f32x2  __attribute__((ext_vector_type(2)));
typedef float f32x4  __attribute__((ext_vector_type(4)));
typedef float f32x16 __attribute__((ext_vector_type(16)));
typedef u32   u32x2  __attribute__((ext_vector_type(2)));
typedef u32   u32x4  __attribute__((ext_vector_type(4)));

#if __has_builtin(__builtin_amdgcn_exp2f)
#define EXP2(x) __builtin_amdgcn_exp2f(x)
#else
#define EXP2(x) __expf((x) * 0.69314718f)
#endif

// counted-vmcnt barrier: wait own loads down to N, then sync, then pin.
#define WAIT_BAR(N) do {                                                      \
    asm volatile("s_waitcnt vmcnt(" #N ")" ::: "memory");                     \
    __builtin_amdgcn_s_barrier();                                             \
    __builtin_amdgcn_sched_barrier(0); } while (0)
#define BAR_ONLY() do {                                                       \
    __builtin_amdgcn_s_barrier();                                             \
    __builtin_amdgcn_sched_barrier(0); } while (0)

__device__ __forceinline__ u16 f2bf_hu(float f) {   // round-half-up (ties rare)
    u32 u = __builtin_bit_cast(u32, f) + 0x8000u;
    return (u16)(u >> 16);
}
// pack two f32 -> dword of two bf16 (lo,hi), 3 VALU ops
__device__ __forceinline__ u32 pk2(float lo, float hi) {
    u32 ul = __builtin_bit_cast(u32, lo) + 0x8000u;
    u32 uh = __builtin_bit_cast(u32, hi) + 0x8000u;
    return __builtin_amdgcn_perm(uh, ul, 0x07060302);  // [uh.hi16 : ul.hi16]
}
// 1-op packed f32->bf16 (RNE); lo -> low16, hi -> high16 (R18-verified)
__device__ __forceinline__ u32 cvtpk(float lo, float hi) {
    u32 r;
    asm("v_cvt_pk_bf16_f32 %0, %1, %2" : "=v"(r) : "v"(lo), "v"(hi));
    return r;
}
__device__ __forceinline__ u16x8 cvt8(const float* s) {
    f32x4 a = *(const f32x4*)s;
    f32x4 b = *(const f32x4*)(s + 4);
    u32x4 r { pk2(a[0], a[1]), pk2(a[2], a[3]), pk2(b[0], b[1]), pk2(b[2], b[3]) };
    return __builtin_bit_cast(u16x8, r);
}
__device__ __forceinline__ f32x4 mfma16(u16x8 a, u16x8 b, f32x4 c) {
    return __builtin_amdgcn_mfma_f32_16x16x32_bf16(
        __builtin_bit_cast(s16x8, a), __builtin_bit_cast(s16x8, b), c, 0, 0, 0);
}
__device__ __forceinline__ f32x16 mfma32(u16x8 a, u16x8 b, f32x16 c) {
    return __builtin_amdgcn_mfma_f32_32x32x16_bf16(
        __builtin_bit_cast(s16x8, a), __builtin_bit_cast(s16x8, b), c, 0, 0, 0);
}
// async global->LDS, 16B per lane.  LDS dest must be wave-uniform base + lane*16.
__device__ __forceinline__ void gld_lds16(const u16* g, u16* l) {
    __builtin_amdgcn_global_load_lds(
        (const __attribute__((address_space(1))) u32*)g,
        (__attribute__((address_space(3))) u32*)l, 16, 0, 0);
}

// ---------------------------------------------------------------------------
// cvt_all: blocks [0,1024): x f32 [8192][1024] -> xb bf16, lane-contiguous.
//          blocks [1024,1792): W[mat][h][1024][64] f32 -> Wt bf16 transposed.
// ---------------------------------------------------------------------------
__global__ __launch_bounds__(256) void cvt_all(
    const float* __restrict__ x,  const float* __restrict__ Wq,
    const float* __restrict__ Wk, const float* __restrict__ Wv,
    u16* __restrict__ xb, u16* __restrict__ Wt)
{
    __shared__ u16 L[64][74];
    const int bx = blockIdx.x;
    if (bx < 1024) {
        const size_t base = (size_t)bx * 8192;
        #pragma unroll
        for (int c = 0; c < 4; c++) {
            const size_t o = base + c * 2048 + threadIdx.x * 8;
            *(u16x8*)(xb + o) = cvt8(x + o);
        }
        return;
    }
    const int wb = bx - 1024;
    const int dblk = wb & 15, h = (wb >> 4) & 15, mat = wb >> 8;
    const float* W = (mat == 0) ? Wq : (mat == 1) ? Wk : Wv;
    const int tid = threadIdx.x;
    {   // load 64(d) x 64(dk), coalesced, convert
        const int dl = tid >> 2, c = (tid & 3) * 16;
        const float* src = W + ((size_t)h * DM_ + dblk * 64 + dl) * D_ + c;
        #pragma unroll
        for (int g = 0; g < 2; g++)
            *(u16x8*)&L[dl][c + g * 8] = cvt8(src + g * 8);
    }
    __syncthreads();
    {   // write rows of Wt: row = dk, 16 d's per thread
        const int dkr = tid >> 2, g = tid & 3;
        u16 tmp[16];
        #pragma unroll
        for (int j = 0; j < 16; j++) tmp[j] = L[g * 16 + j][dkr];
        u16* dst = Wt + ((size_t)(mat * 16 + h) * 64 + dkr) * DM_ + dblk * 64 + g * 16;
        *(u16x8*)dst = *(u16x8*)tmp;
        *(u16x8*)(dst + 8) = *(u16x8*)(tmp + 8);
    }
}

// ---------------------------------------------------------------------------
// Projection GEMM: C[8192][3072] = xb @ Wt^T (Wt rows are C-columns).
// 1536 blocks, 256 thr = 4 waves 2x2, 128x128 tile, BK=64.
// XCD m-slice mapping: XCD x owns m-tiles [8x,8x+8) x all 24 n, m-fastest.
// Counted-vmcnt pipeline: 8 gld_lds per STAGE per wave; vmcnt(8) steady.
// ---------------------------------------------------------------------------
template<int SWAP>
__device__ __forceinline__ void pcompute(const char* Asb, const char* Bsb,
                                         int wm, int wn, int quad, int l16,
                                         int ax, f32x4 (&acc)[4][4]) {
    #pragma unroll
    for (int ks = 0; ks < 2; ks++) {
        u16x8 af[4], bf[4];
        #pragma unroll
        for (int i = 0; i < 4; i++)
            af[i] = *(const u16x8*)(Asb +
                ((((wm * 64 + i * 16 + l16) * 64 + ks * 32 + quad * 8) * 2) ^ ax));
        #pragma unroll
        for (int j = 0; j < 4; j++)
            bf[j] = *(const u16x8*)(Bsb +
                ((((wn * 64 + j * 16 + l16) * 64 + ks * 32 + quad * 8) * 2) ^ ax));
        __builtin_amdgcn_s_setprio(1);
        #pragma unroll
        for (int i = 0; i < 4; i++)
            #pragma unroll
            for (int j = 0; j < 4; j++)
                acc[i][j] = SWAP ? mfma16(bf[j], af[i], acc[i][j])
                                 : mfma16(af[i], bf[j], acc[i][j]);
        __builtin_amdgcn_s_setprio(0);
    }
}

__global__ __launch_bounds__(256) void proj_kernel(
    const u16* __restrict__ xb, const u16* __restrict__ Wt,
    u16* __restrict__ Qc, u16* __restrict__ Kc, u16* __restrict__ Vtc)
{
    __shared__ __attribute__((aligned(16))) u16 As0[128][64];
    __shared__ __attribute__((aligned(16))) u16 Bs0[128][64];
    __shared__ __attribute__((aligned(16))) u16 As1[128][64];
    __shared__ __attribute__((aligned(16))) u16 Bs1[128][64];

    // XCD m-slice supertiling: pb = xcd + 8*mid + 64*ntile (bijective).
    const int pb = blockIdx.x;
    const int mt = (pb & 7) * 8 + ((pb >> 3) & 7);   // m-tile 0..63
    const int nti = pb >> 6;                         // n-tile 0..23
    const int m0 = mt * 128;
    const int n0 = nti * 128;                 // n = mat*1024 + h*64 + dk
    const int mat = n0 >> 10;
    const int tid  = threadIdx.x;
    const int wave = tid >> 6, lane = tid & 63;
    const int quad = lane >> 4, l16 = lane & 15;
    const int wm   = wave >> 1, wn = wave & 1;

    const int r8 = lane >> 3, g8 = lane & 7;
    const int gs = (g8 ^ r8) * 8;             // pre-swizzled source col (u16)
    const int ax = (l16 & 7) << 4;            // read-side byte XOR

    f32x4 acc[4][4];
    #pragma unroll
    for (int i = 0; i < 4; i++)
        #pragma unroll
        for (int j = 0; j < 4; j++) acc[i][j] = f32x4{0.f, 0.f, 0.f, 0.f};

    auto STAGE = [&](u16* Ad, u16* Bd, int kb) {
        const int kbase = kb * 64;
        #pragma unroll
        for (int it = 0; it < 4; it++) {
            const int row = it * 32 + wave * 8 + r8;
            const int ldo = (it * 4 + wave) * 512 + lane * 8;   // u16 units
            gld_lds16(xb + (size_t)(m0 + row) * DM_ + kbase + gs, Ad + ldo);
            gld_lds16(Wt + (size_t)(n0 + row) * DM_ + kbase + gs, Bd + ldo);
        }
    };

    STAGE(&As0[0][0], &Bs0[0][0], 0);
    STAGE(&As1[0][0], &Bs1[0][0], 1);        // 16 outstanding / wave

    #define PLOOP(SW)                                                        \
        for (int j = 0; j < 8; j++) {                                        \
            WAIT_BAR(8);                                                     \
            pcompute<SW>((const char*)As0, (const char*)Bs0,                 \
                         wm, wn, quad, l16, ax, acc);                        \
            BAR_ONLY();                                                      \
            if (2 * j + 2 < 16) STAGE(&As0[0][0], &Bs0[0][0], 2 * j + 2);    \
            if (j < 7) { WAIT_BAR(8); } else { WAIT_BAR(0); }                \
            pcompute<SW>((const char*)As1, (const char*)Bs1,                 \
                         wm, wn, quad, l16, ax, acc);                        \
            BAR_ONLY();                                                      \
            if (2 * j + 3 < 16) STAGE(&As1[0][0], &Bs1[0][0], 2 * j + 3);    \
        }
    if (mat != 2) { PLOOP(1) } else { PLOOP(0) }
    #undef PLOOP

    const int h_base = (n0 & 1023) >> 6;
    if (mat != 2) {
        // SWAPPED: r walks dk.
        u16* Cm = (mat == 0) ? Qc : Kc;
        const float sc = (mat == 0) ? 0.18033688f : 1.0f;  // Q: dk^-.5*log2e
        #pragma unroll
        for (int i = 0; i < 4; i++) {
            const int m  = m0 + wm * 64 + i * 16 + l16;
            const int bb = m >> 11, t = m & (T_ - 1);
            u16* rowp = Cm + ((size_t)(bb * H_ + h_base + wn) * T_ + t) * D_;
            #pragma unroll
            for (int j = 0; j < 4; j++) {
                const int dk0 = j * 16 + quad * 4;
                u32x2 d { pk2(acc[i][j][0] * sc, acc[i][j][1] * sc),
                          pk2(acc[i][j][2] * sc, acc[i][j][3] * sc) };
                *(u32x2*)(rowp + dk0) = d;
            }
        }
    } else {
        // NORMAL: r walks t.
        #pragma unroll
        for (int i = 0; i < 4; i++) {
            const int m  = m0 + wm * 64 + i * 16 + quad * 4;   // r = 0 base
            const int bb = m >> 11, t = m & (T_ - 1);
            #pragma unroll
            for (int j = 0; j < 4; j++) {
                const int dk = j * 16 + l16;
                u32x2 d { pk2(acc[i][j][0], acc[i][j][1]),
                          pk2(acc[i][j][2], acc[i][j][3]) };
                *(u32x2*)(Vtc + ((size_t)(bb * H_ + h_base + wn) * D_ + dk) * T_ + t) = d;
            }
        }
    }
}

// ---------------------------------------------------------------------------
// Flash attention, swapped-operand (S^T = K.Q^T via 32x32x16 MFMA).
// 8-wave blocks: 512 thr own 256 consecutive q-rows.  K/V tile staged once
// per block.  512 blocks, SAME-G CU packing: cu = pb&255 (round-robin
// dispatch slot), g = cu>>5, bh = (cu&31)*2 + (pb>>8) -> both blocks on a
// CU share g and run their full 4g+4 tiles concurrently (no solo tail on
// the wall CUs).  Counted-vmcnt double buffer; R18-verified exchanges.
// ---------------------------------------------------------------------------
__global__ __launch_bounds__(512, 2) void attn_kernel(
    const u16* __restrict__ Qc, const u16* __restrict__ Kc,
    const u16* __restrict__ Vtc, float* __restrict__ out)
{
    __shared__ __attribute__((aligned(16))) u16 Ks0[64][64];  // swz [s][k]
    __shared__ __attribute__((aligned(16))) u16 Vs0[64][64];  // swz [dv][s]
    __shared__ __attribute__((aligned(16))) u16 Ks1[64][64];
    __shared__ __attribute__((aligned(16))) u16 Vs1[64][64];

    const int pb  = blockIdx.x;
    const int cu  = pb & 255;                 // dispatch slot (rr over CUs)
    const int g   = cu >> 5;                  // 32 CUs per g-class
    const int bh  = ((cu & 31) << 1) | (pb >> 8);   // bijective over blocks
    const int h   = bh & 15, b = bh >> 4;

    const int tid = threadIdx.x, w = tid >> 6, lane = tid & 63;
    const int l31 = lane & 31, hi = lane >> 5;
    const int r8 = (tid >> 3) & 7, g8 = tid & 7;
    const int gs = (g8 ^ r8) * 8;             // pre-swizzled source col (u16)
    const int ax = (l31 & 7) << 4;            // read-side byte XOR

    const int qrow = g * 256 + w * 32 + l31;  // this lane's q (S^T column)
    const int i_d  = g * 4 + (w >> 1);        // wave's diagonal s-tile
    const int nt   = g * 4 + 4;               // s-tiles this block stages
    const int qmask = 32 * (w & 1) + l31;     // q within the diagonal tile

    const u16* Qbh = Qc + (size_t)(b * H_ + h) * T_ * D_;
    const u16* Kbh = Kc + (size_t)(b * H_ + h) * T_ * D_;
    const u16* Vbh = Vtc + (size_t)(b * H_ + h) * D_ * T_;

    auto STAGE = [&](u16* Kd, u16* Vd, int t) {
        const int sbase = t * 64;
        const int row = tid >> 3;             // 512 thr cover 64 rows x 8 gran
        const int ldo = tid * 8;              // u16 units (lane*16B, wave-lin)
        gld_lds16(Kbh + (size_t)(sbase + row) * D_ + gs, Kd + ldo);
        gld_lds16(Vbh + (size_t)row * T_ + sbase + gs,  Vd + ldo);
    };

    // Q B-frags (col=lane&31=q, k = hi*8+e per 16-chunk), scaled at proj.
    u16x8 qf[4];
    #pragma unroll
    for (int ks = 0; ks < 4; ks++)
        qf[ks] = *(const u16x8*)(Qbh + (size_t)qrow * D_ + ks * 16 + hi * 8);

    // loop-invariant zero accumulator (hoisted out of the tile loop)
    f32x16 zz;
    #pragma unroll
    for (int r = 0; r < 16; r++) zz[r] = 0.f;

    f32x16 ot0, ot1;                          // O^T accum: dv 0..31 / 32..63
    #pragma unroll
    for (int r = 0; r < 16; r++) { ot0[r] = 0.f; ot1[r] = 0.f; }
    float mi = -1e30f, li = 0.f;

    auto COMPUTE = [&](const char* Ksb, const char* Vsb, int i) {
        // S^T = K . Q^T   (two 32-s tiles, log2 domain); ks=0 inits from zz
        f32x16 st0, st1;
        __builtin_amdgcn_s_setprio(1);
        {
            const int co = (hi * 8) * 2;                        // ks = 0
            u16x8 k0 = *(const u16x8*)(Ksb + ((l31 * 128 + co) ^ ax));
            u16x8 k1 = *(const u16x8*)(Ksb + (((32 + l31) * 128 + co) ^ ax));
            st0 = mfma32(k0, qf[0], zz);
            st1 = mfma32(k1, qf[0], zz);
        }
        #pragma unroll
        for (int ks = 1; ks < 4; ks++) {
            const int co = (ks * 16 + hi * 8) * 2;              // byte col
            u16x8 k0 = *(const u16x8*)(Ksb + ((l31 * 128 + co) ^ ax));
            u16x8 k1 = *(const u16x8*)(Ksb + (((32 + l31) * 128 + co) ^ ax));
            st0 = mfma32(k0, qf[ks], st0);
            st1 = mfma32(k1, qf[ks], st1);
        }
        __builtin_amdgcn_s_setprio(0);

        // causal mask — only the wave's diagonal s-tile is partial
        if (i == i_d) {
            #pragma unroll
            for (int r = 0; r < 16; r++) {
                const int sl = (r & 3) + 8 * (r >> 2) + 4 * hi;
                if (sl > qmask)      st0[r] = -1e30f;
                if (sl + 32 > qmask) st1[r] = -1e30f;
            }
        }

        // max: v_max3-fused tree + lane^32 combine via shfl (R18-verified)
        float mx = fmaxf(st0[0], st0[1]);
        #pragma unroll
        for (int r = 2; r < 16; r += 2) mx = fmaxf(fmaxf(mx, st0[r]), st0[r + 1]);
        #pragma unroll
        for (int r = 0; r < 16; r += 2) mx = fmaxf(fmaxf(mx, st1[r]), st1[r + 1]);
        mx = fmaxf(mx, __shfl_xor(mx, 32));
        if (!__all(mx - mi <= 8.f)) {         // defer-max (T13, THR=8)
            const float mn = fmaxf(mi, mx);
            const float al = EXP2(mi - mn);
            li *= al;
            #pragma unroll
            for (int r = 0; r < 16; r++) { ot0[r] *= al; ot1[r] *= al; }
            mi = mn;
        }

        // packed sub + exp + packed accumulate
        f32x2 mm; mm[0] = mi; mm[1] = mi;
        f32x2 sac; sac[0] = 0.f; sac[1] = 0.f;
        #pragma unroll
        for (int k = 0; k < 8; k++) {
            f32x2 a; a[0] = st0[2 * k]; a[1] = st0[2 * k + 1];
            f32x2 c; c[0] = st1[2 * k]; c[1] = st1[2 * k + 1];
            a = a - mm; c = c - mm;
            a[0] = EXP2(a[0]); a[1] = EXP2(a[1]);
            c[0] = EXP2(c[0]); c[1] = EXP2(c[1]);
            st0[2 * k] = a[0]; st0[2 * k + 1] = a[1];
            st1[2 * k] = c[0]; st1[2 * k + 1] = c[1];
            sac = sac + a; sac = sac + c;
        }
        float sum = sac[0] + sac[1];
        sum += __shfl_xor(sum, 32);
        li += sum;

        // P^T -> PV B-frags: cvt_pk pairs + R18-VERIFIED shfl exchange.
        // hi=0 -> {own d0, own d1, partner d0, partner d1};
        // hi=1 -> {partner d2, partner d3, own d2, own d3}.
        u16x8 pb4[4];
        #define PACK(SRC, C, OUT) {                                           \
            u32 d0 = cvtpk(SRC[8*(C)+0], SRC[8*(C)+1]);                       \
            u32 d1 = cvtpk(SRC[8*(C)+2], SRC[8*(C)+3]);                       \
            u32 d2 = cvtpk(SRC[8*(C)+4], SRC[8*(C)+5]);                       \
            u32 d3 = cvtpk(SRC[8*(C)+6], SRC[8*(C)+7]);                       \
            u32 e0 = __shfl_xor(hi ? d0 : d2, 32);                            \
            u32 e1 = __shfl_xor(hi ? d1 : d3, 32);                            \
            u32x4 wds{ hi ? e0 : d0, hi ? e1 : d1,                            \
                       hi ? d2 : e0, hi ? d3 : e1 };                          \
            OUT = __builtin_bit_cast(u16x8, wds); }
        PACK(st0, 0, pb4[0]); PACK(st0, 1, pb4[1]);
        PACK(st1, 0, pb4[2]); PACK(st1, 1, pb4[3]);
        #undef PACK

        // O^T += V^T . P^T  (A rows = dv, k = s)
        __builtin_amdgcn_s_setprio(1);
        #pragma unroll
        for (int kc = 0; kc < 4; kc++) {
            const int co = (kc * 16 + hi * 8) * 2;
            u16x8 v0 = *(const u16x8*)(Vsb + ((l31 * 128 + co) ^ ax));
            u16x8 v1 = *(const u16x8*)(Vsb + (((32 + l31) * 128 + co) ^ ax));
            ot0 = mfma32(v0, pb4[kc], ot0);
            ot1 = mfma32(v1, pb4[kc], ot1);
        }
        __builtin_amdgcn_s_setprio(0);
    };

    STAGE(&Ks0[0][0], &Vs0[0][0], 0);
    STAGE(&Ks1[0][0], &Vs1[0][0], 1);         // 4 outstanding / lane

    const int np = nt >> 1;                   // nt is even (4g+4)
    for (int j = 0; j < np; j++) {
        const int i0 = 2 * j, i1 = 2 * j + 1;
        WAIT_BAR(2);
        if (i0 <= i_d) COMPUTE((const char*)Ks0, (const char*)Vs0, i0);
        BAR_ONLY();
        if (i0 + 2 < nt) STAGE(&Ks0[0][0], &Vs0[0][0], i0 + 2);
        if (j < np - 1) { WAIT_BAR(2); } else { WAIT_BAR(0); }
        if (i1 <= i_d) COMPUTE((const char*)Ks1, (const char*)Vs1, i1);
        BAR_ONLY();
        if (i1 + 2 < nt) STAGE(&Ks1[0][0], &Vs1[0][0], i1 + 2);
    }

    // output: O^T reg r -> dv = td*32 + 16c + 8hf + 4hi + j, q = qrow
    const float inv = 1.0f / li;
    float* orow = out + (size_t)(b * T_ + qrow) * DMO + h * D_;
    #pragma unroll
    for (int c = 0; c < 2; c++)
        #pragma unroll
        for (int hf = 0; hf < 2; hf++) {
            f32x4 v0, v1;
            #pragma unroll
            for (int j = 0; j < 4; j++) {
                v0[j] = ot0[c * 8 + hf * 4 + j] * inv;
                v1[j] = ot1[c * 8 + hf * 4 + j] * inv;
            }
            *(f32x4*)(orow + c * 16 + hf * 8 + hi * 4)      = v0;
            *(f32x4*)(orow + 32 + c * 16 + hf * 8 + hi * 4) = v1;
        }
}

// ---------------------------------------------------------------------------
extern "C" void kernel_launch(void* const* d_in, const int* in_sizes, int n_in,
                              void* d_out, int out_size, void* d_ws, size_t ws_size,
                              hipStream_t stream) {
    int xi = 0, wi[3] = {1, 2, 3};
    {
        int k = 0, found = 0;
        for (int i = 0; i < n_in && i < 8; i++) {
            if (in_sizes[i] == B_ * T_ * DM_) { xi = i; found = 1; }
            else if (in_sizes[i] == H_ * DM_ * D_ && k < 3) wi[k++] = i;
        }
        if (!found || k != 3) { xi = 0; wi[0] = 1; wi[1] = 2; wi[2] = 3; }
    }
    const float* x  = (const float*)d_in[xi];
    const float* Wq = (const float*)d_in[wi[0]];
    const float* Wk = (const float*)d_in[wi[1]];
    const float* Wv = (const float*)d_in[wi[2]];
    float* out = (float*)d_out;

    // bf16 staging scratch lives in d_out (dead before attn writes it):
    //   xb = 8.4M u16 (16.8 MB), Wt = 3.1M u16 (6.3 MB) -> 23.1 of 33.5 MB.
    u16* xb = (u16*)d_out;
    u16* Wt = xb + (size_t)B_ * T_ * DM_;
    // ws: Q + K + Vt bf16 = 50.3 MB (R8-verified to fit).
    const size_t per = (size_t)B_ * H_ * T_ * D_;
    u16* Qc  = (u16*)d_ws;
    u16* Kc  = Qc + per;
    u16* Vtc = Kc + per;

    cvt_all<<<1792, 256, 0, stream>>>(x, Wq, Wk, Wv, xb, Wt);
    proj_kernel<<<1536, 256, 0, stream>>>(xb, Wt, Qc, Kc, Vtc);
    attn_kernel<<<512, 512, 0, stream>>>(Qc, Kc, Vtc, out);
}